// Round 1
// baseline (365.927 us; speedup 1.0000x reference)
//
#include <hip/hip_runtime.h>
#include <hip/hip_bf16.h>
#include <stdint.h>

#define DIN   4096
#define DOUT  4096
#define MTOT  8192
#define BK    32
#define KTILES (DIN / BK)

typedef float f32x4  __attribute__((ext_vector_type(4)));
typedef short bf16x8 __attribute__((ext_vector_type(8)));

__device__ __forceinline__ ushort f2bf(float f) {
  __hip_bfloat16 h = __float2bfloat16(f);  // RNE
  ushort r;
  __builtin_memcpy(&r, &h, sizeof(r));
  return r;
}

__device__ __forceinline__ void glds16(const void* g, void* l) {
  __builtin_amdgcn_global_load_lds(
      (__attribute__((address_space(1))) void*)g,
      (__attribute__((address_space(3))) void*)l, 16, 0, 0);
}

// ---------------------------------------------------------------------------
// Kernel 1: per-row alpha (fp64 accumulate) + ternary quantize -> bf16
// ---------------------------------------------------------------------------
__global__ __launch_bounds__(256) void quant_kernel(const float* __restrict__ W,
                                                    ushort* __restrict__ QW) {
  const int row = blockIdx.x;
  const int t = threadIdx.x;
  const float* wr = W + (size_t)row * DIN;

  float4 v[4];
  double s = 0.0;
#pragma unroll
  for (int j = 0; j < 4; ++j) {
    v[j] = reinterpret_cast<const float4*>(wr)[j * 256 + t];
    s += (double)fabsf(v[j].x) + (double)fabsf(v[j].y) +
         (double)fabsf(v[j].z) + (double)fabsf(v[j].w);
  }
#pragma unroll
  for (int off = 32; off > 0; off >>= 1) s += __shfl_down(s, off, 64);

  __shared__ double ssum[4];
  __shared__ float salpha;
  if ((t & 63) == 0) ssum[t >> 6] = s;
  __syncthreads();
  if (t == 0) salpha = (float)((ssum[0] + ssum[1] + ssum[2] + ssum[3]) / (double)DIN);
  __syncthreads();
  const float alpha = salpha;

  ushort4* qo = reinterpret_cast<ushort4*>(QW + (size_t)row * DIN);
#pragma unroll
  for (int j = 0; j < 4; ++j) {
    ushort4 q;
    q.x = v[j].x > alpha ? 0x3F80 : (v[j].x < -alpha ? 0xBF80 : 0);
    q.y = v[j].y > alpha ? 0x3F80 : (v[j].y < -alpha ? 0xBF80 : 0);
    q.z = v[j].z > alpha ? 0x3F80 : (v[j].z < -alpha ? 0xBF80 : 0);
    q.w = v[j].w > alpha ? 0x3F80 : (v[j].w < -alpha ? 0xBF80 : 0);
    qo[j * 256 + t] = q;
  }
}

// ---------------------------------------------------------------------------
// Kernel 2: x fp32 -> bf16 (used only when workspace is large enough)
// ---------------------------------------------------------------------------
__global__ __launch_bounds__(256) void cvt_kernel(const float* __restrict__ X,
                                                  ushort* __restrict__ XB, int n4) {
  int idx = blockIdx.x * 256 + threadIdx.x;
  const int stride = gridDim.x * 256;
  for (int i = idx; i < n4; i += stride) {
    float4 v = reinterpret_cast<const float4*>(X)[i];
    ushort4 o;
    o.x = f2bf(v.x); o.y = f2bf(v.y); o.z = f2bf(v.z); o.w = f2bf(v.w);
    reinterpret_cast<ushort4*>(XB)[i] = o;
  }
}

// ---------------------------------------------------------------------------
// Kernel 3: bf16 MFMA GEMM. out[m][n] = (x @ qw^T)[m][n]*scale[n] + bias[n]
// 128x128 tile, BK=32, 256 threads = 4 waves in 2x2, each wave 64x64.
// PRE=true : A staged via global_load_lds from pre-converted bf16 x.
// PRE=false: A reg-staged from fp32 x with in-register bf16 conversion.
// ---------------------------------------------------------------------------
template <bool PRE>
__global__ __launch_bounds__(256, 2) void gemm_kernel(
    const float* __restrict__ X, const ushort* __restrict__ XB,
    const ushort* __restrict__ QW, const float* __restrict__ scale,
    const float* __restrict__ bias, float* __restrict__ out) {
  __shared__ ushort Al[2][128 * BK];  // 8 KB each
  __shared__ ushort Bl[2][128 * BK];

  const int t = threadIdx.x;
  const int lane = t & 63;
  const int wid = t >> 6;
  const int wr = wid >> 1, wc = wid & 1;  // 2x2 wave grid
  const int m0 = blockIdx.x * 128;
  const int n0 = blockIdx.y * 128;

  f32x4 acc[4][4] = {};  // [mi][ni]

  const ushort* bg  = QW + (size_t)n0 * DIN;
  const ushort* agb = XB + (size_t)m0 * DIN;
  const float*  ag  = X  + (size_t)m0 * DIN;

  float4 areg[4];

  // glds chunk mapping: chunk = i*256+t (16B each); row = chunk>>2; k-off = (chunk&3)*8 elems
  auto stageB = [&](int kt, int buf) {
    const ushort* src = bg + kt * BK;
#pragma unroll
    for (int i = 0; i < 2; ++i)
      glds16(src + (size_t)(i * 64 + (t >> 2)) * DIN + (t & 3) * 8,
             &Bl[buf][(i * 256 + t) * 8]);
  };
  auto stageA_glds = [&](int kt, int buf) {
    const ushort* src = agb + kt * BK;
#pragma unroll
    for (int i = 0; i < 2; ++i)
      glds16(src + (size_t)(i * 64 + (t >> 2)) * DIN + (t & 3) * 8,
             &Al[buf][(i * 256 + t) * 8]);
  };
  // reg-staged A: chunk = j*256+t (4 floats); row = chunk>>3; k-off = (chunk&7)*4
  auto loadA_reg = [&](int kt) {
#pragma unroll
    for (int j = 0; j < 4; ++j)
      areg[j] = *reinterpret_cast<const float4*>(
          ag + (size_t)(j * 32 + (t >> 3)) * DIN + kt * BK + (t & 7) * 4);
  };
  auto writeA_reg = [&](int buf) {
#pragma unroll
    for (int j = 0; j < 4; ++j) {
      ushort4 o;
      o.x = f2bf(areg[j].x); o.y = f2bf(areg[j].y);
      o.z = f2bf(areg[j].z); o.w = f2bf(areg[j].w);
      *reinterpret_cast<ushort4*>(&Al[buf][(j * 256 + t) * 4]) = o;
    }
  };
  auto compute = [&](int buf) {
    const int r = lane & 15;
    const int kq = lane >> 4;  // 8 consecutive k at kq*8
    bf16x8 af[4], bfr[4];
#pragma unroll
    for (int mi = 0; mi < 4; ++mi)
      af[mi] = *reinterpret_cast<const bf16x8*>(
          &Al[buf][(wr * 64 + mi * 16 + r) * BK + kq * 8]);
#pragma unroll
    for (int ni = 0; ni < 4; ++ni)
      bfr[ni] = *reinterpret_cast<const bf16x8*>(
          &Bl[buf][(wc * 64 + ni * 16 + r) * BK + kq * 8]);
#pragma unroll
    for (int mi = 0; mi < 4; ++mi)
#pragma unroll
      for (int ni = 0; ni < 4; ++ni)
        acc[mi][ni] = __builtin_amdgcn_mfma_f32_16x16x32_bf16(
            af[mi], bfr[ni], acc[mi][ni], 0, 0, 0);
  };

  // prologue: tile 0 into buf 0
  if (PRE) {
    stageA_glds(0, 0);
  } else {
    loadA_reg(0);
  }
  stageB(0, 0);
  if (!PRE) writeA_reg(0);
  __syncthreads();

  int cur = 0;
  for (int kt = 0; kt < KTILES; ++kt) {
    if (kt + 1 < KTILES) {  // prefetch next tile into buf cur^1
      if (PRE) stageA_glds(kt + 1, cur ^ 1);
      else     loadA_reg(kt + 1);
      stageB(kt + 1, cur ^ 1);
    }
    compute(cur);
    if (kt + 1 < KTILES) {
      if (!PRE) writeA_reg(cur ^ 1);
      __syncthreads();  // drains glds (vmcnt) + ds_writes before swap
      cur ^= 1;
    }
  }

  // epilogue: D lane map col=lane&15, row=(lane>>4)*4+e  (m89-verified)
  const int r = lane & 15;
  const int q4 = lane >> 4;
#pragma unroll
  for (int ni = 0; ni < 4; ++ni) {
    const int col = n0 + wc * 64 + ni * 16 + r;
    const float sc = scale[col];
    const float bs = bias[col];
#pragma unroll
    for (int mi = 0; mi < 4; ++mi) {
      const int row = m0 + wr * 64 + mi * 16 + q4 * 4;
#pragma unroll
      for (int e = 0; e < 4; ++e)
        out[(size_t)(row + e) * DOUT + col] = acc[mi][ni][e] * sc + bs;
    }
  }
}

extern "C" void kernel_launch(void* const* d_in, const int* in_sizes, int n_in,
                              void* d_out, int out_size, void* d_ws, size_t ws_size,
                              hipStream_t stream) {
  const float* X     = (const float*)d_in[0];
  const float* W     = (const float*)d_in[1];
  const float* scale = (const float*)d_in[2];
  const float* bias  = (const float*)d_in[3];
  float* out = (float*)d_out;

  const size_t qw_bytes = (size_t)DOUT * DIN * sizeof(ushort);          // 32 MB
  const size_t xb_bytes = (size_t)MTOT * DIN * sizeof(ushort);          // 64 MB
  ushort* QW = (ushort*)d_ws;
  ushort* XB = (ushort*)((char*)d_ws + qw_bytes);

  quant_kernel<<<DOUT, 256, 0, stream>>>(W, QW);

  dim3 grid(MTOT / 128, DOUT / 128);
  if (ws_size >= qw_bytes + xb_bytes) {
    cvt_kernel<<<2048, 256, 0, stream>>>(X, XB, MTOT * DIN / 4);
    gemm_kernel<true><<<grid, 256, 0, stream>>>(X, XB, QW, scale, bias, out);
  } else {
    gemm_kernel<false><<<grid, 256, 0, stream>>>(X, XB, QW, scale, bias, out);
  }
}

// Round 3
// 314.503 us; speedup vs baseline: 1.1635x; 1.1635x over previous
//
#include <hip/hip_runtime.h>
#include <hip/hip_bf16.h>
#include <stdint.h>

#define DIN   4096
#define DOUT  4096
#define MTOT  8192

// old 128^2 fallback geometry
#define BK32   32
#define KT128  (DIN / BK32)
// 256^2 8-phase geometry
#define BK64   64
#define NKT    (DIN / BK64)   // 64 K-tiles

typedef float f32x4  __attribute__((ext_vector_type(4)));
typedef short bf16x8 __attribute__((ext_vector_type(8)));

__device__ __forceinline__ ushort f2bf(float f) {
  __hip_bfloat16 h = __float2bfloat16(f);  // RNE
  ushort r;
  __builtin_memcpy(&r, &h, sizeof(r));
  return r;
}

__device__ __forceinline__ void glds16(const void* g, void* l) {
  __builtin_amdgcn_global_load_lds(
      (__attribute__((address_space(1))) void*)g,
      (__attribute__((address_space(3))) void*)l, 16, 0, 0);
}

// ---------------------------------------------------------------------------
// Kernel 1: per-row alpha (fp64 accumulate) + ternary quantize -> bf16
// ---------------------------------------------------------------------------
__global__ __launch_bounds__(256) void quant_kernel(const float* __restrict__ W,
                                                    ushort* __restrict__ QW) {
  const int row = blockIdx.x;
  const int t = threadIdx.x;
  const float* wr = W + (size_t)row * DIN;

  float4 v[4];
  double s = 0.0;
#pragma unroll
  for (int j = 0; j < 4; ++j) {
    v[j] = reinterpret_cast<const float4*>(wr)[j * 256 + t];
    s += (double)fabsf(v[j].x) + (double)fabsf(v[j].y) +
         (double)fabsf(v[j].z) + (double)fabsf(v[j].w);
  }
#pragma unroll
  for (int off = 32; off > 0; off >>= 1) s += __shfl_down(s, off, 64);

  __shared__ double ssum[4];
  __shared__ float salpha;
  if ((t & 63) == 0) ssum[t >> 6] = s;
  __syncthreads();
  if (t == 0) salpha = (float)((ssum[0] + ssum[1] + ssum[2] + ssum[3]) / (double)DIN);
  __syncthreads();
  const float alpha = salpha;

  ushort4* qo = reinterpret_cast<ushort4*>(QW + (size_t)row * DIN);
#pragma unroll
  for (int j = 0; j < 4; ++j) {
    ushort4 q;
    q.x = v[j].x > alpha ? 0x3F80 : (v[j].x < -alpha ? 0xBF80 : 0);
    q.y = v[j].y > alpha ? 0x3F80 : (v[j].y < -alpha ? 0xBF80 : 0);
    q.z = v[j].z > alpha ? 0x3F80 : (v[j].z < -alpha ? 0xBF80 : 0);
    q.w = v[j].w > alpha ? 0x3F80 : (v[j].w < -alpha ? 0xBF80 : 0);
    qo[j * 256 + t] = q;
  }
}

// ---------------------------------------------------------------------------
// Kernel 2: x fp32 -> bf16
// ---------------------------------------------------------------------------
__global__ __launch_bounds__(256) void cvt_kernel(const float* __restrict__ X,
                                                  ushort* __restrict__ XB, int n4) {
  int idx = blockIdx.x * 256 + threadIdx.x;
  const int stride = gridDim.x * 256;
  for (int i = idx; i < n4; i += stride) {
    float4 v = reinterpret_cast<const float4*>(X)[i];
    ushort4 o;
    o.x = f2bf(v.x); o.y = f2bf(v.y); o.z = f2bf(v.z); o.w = f2bf(v.w);
    reinterpret_cast<ushort4*>(XB)[i] = o;
  }
}

// ---------------------------------------------------------------------------
// Kernel 3: 256x256 8-phase bf16 MFMA GEMM (T2+T3+T4+T5 structure).
// out[m][n] = (x @ qw^T)[m][n]*scale[n] + bias[n]
// 512 thr = 8 waves (2Mx4N), each wave 128x64 out, BK=64, 4 phases/K-tile.
// LDS: A/B tiles [256 rows][64 k] bf16, double-buffered = 128 KiB.
// Swizzle: 16B chunk index XORed with (row&7); glds dest linear, source
// inverse-swizzled per-lane (rule #21), ds_read applies same XOR.
//
// Issue schedule (race-audited, round-2 fix): a wave with wr reads BOTH A
// halves of its 128-row block across phases 1 AND 3, so A[buf] may only be
// overwritten after ph3's lgkmcnt(0)+barrier. B[buf] reads finish at ph2.
//   ph1: issue B.h1(T+1)   (region last read: tile T-1 ph2)
//   ph2: no issue
//   ph3: issue B.h0(T+2)   (B[buf] reads done at ph2 SYNC_END)
//   ph4: issue A.h0+A.h1(T+2)  (A[buf] reads done at ph3 SYNC_END)
// vmcnt ledger: after B_{T+1}.h1 only 3 halves (6 loads) follow in the
// stream at the ph4 wait -> vmcnt(6) == tile T+1 fully landed.
// ---------------------------------------------------------------------------
__global__ __launch_bounds__(512, 2) void gemm256_kernel(
    const ushort* __restrict__ XB, const ushort* __restrict__ QW,
    const float* __restrict__ scale, const float* __restrict__ bias,
    float* __restrict__ out) {
  __shared__ ushort As[2][16384];  // 32 KB each buf
  __shared__ ushort Bs[2][16384];

  const int t = threadIdx.x;
  const int lane = t & 63;
  const int wid = t >> 6;
  const int wr = wid >> 2, wc = wid & 3;          // 2x4 wave grid
  const int m0 = blockIdx.x * 256;
  const int n0 = blockIdx.y * 256;

  const ushort* ag = XB + (size_t)m0 * DIN;
  const ushort* bg = QW + (size_t)n0 * DIN;

  f32x4 acc[8][4] = {};          // [m-frag 0..7][n-frag 0..3]
  bf16x8 a[4][2];                // current A half: 4 m-frags x 2 k-steps
  bf16x8 b0[2][2], b1[2][2];     // B halves kept live across the tile

  const int r = lane & 15, kq = lane >> 4;
  const int srow = t >> 3;                         // 0..63
  const int srcc = ((t & 7) ^ ((t >> 3) & 7)) * 8; // inverse-swizzled src chunk (elems)

// issue one half-tile: tile Tt, q: 0=A.h0 1=B.h0 2=A.h1 3=B.h1
#define ISSUE_H(Tt_, q_) do {                                                   \
    const int T_ = (Tt_);                                                       \
    if (T_ < NKT) {                                                             \
      const int q__ = (q_), hf_ = q__ >> 1, bf_ = T_ & 1;                       \
      const ushort* gb_ = (q__ & 1) ? bg : ag;                                  \
      ushort* lb_ = (q__ & 1) ? &Bs[bf_][0] : &As[bf_][0];                      \
      glds16(gb_ + (size_t)(hf_ * 128 + srow) * DIN + T_ * 64 + srcc,           \
             lb_ + hf_ * 8192 + t * 8);                                         \
      glds16(gb_ + (size_t)(hf_ * 128 + 64 + srow) * DIN + T_ * 64 + srcc,      \
             lb_ + hf_ * 8192 + 4096 + t * 8);                                  \
    }                                                                           \
  } while (0)

#define READA(buf_, mh_) do {                                                   \
    _Pragma("unroll")                                                           \
    for (int mi = 0; mi < 4; ++mi) {                                            \
      const int row_ = wr * 128 + ((mh_) * 4 + mi) * 16 + r;                    \
      a[mi][0] = *reinterpret_cast<const bf16x8*>(                              \
          &As[buf_][row_ * 64 + ((0 + kq) ^ (r & 7)) * 8]);                     \
      a[mi][1] = *reinterpret_cast<const bf16x8*>(                              \
          &As[buf_][row_ * 64 + ((4 + kq) ^ (r & 7)) * 8]);                     \
    }                                                                           \
  } while (0)

#define READB(buf_, nh_, breg) do {                                             \
    _Pragma("unroll")                                                           \
    for (int ni = 0; ni < 2; ++ni) {                                            \
      const int row_ = wc * 64 + ((nh_) * 2 + ni) * 16 + r;                     \
      breg[ni][0] = *reinterpret_cast<const bf16x8*>(                           \
          &Bs[buf_][row_ * 64 + ((0 + kq) ^ (r & 7)) * 8]);                     \
      breg[ni][1] = *reinterpret_cast<const bf16x8*>(                           \
          &Bs[buf_][row_ * 64 + ((4 + kq) ^ (r & 7)) * 8]);                     \
    }                                                                           \
  } while (0)

#define MMA(mh_, nh_, breg) do {                                                \
    __builtin_amdgcn_s_setprio(1);                                              \
    _Pragma("unroll")                                                           \
    for (int mi = 0; mi < 4; ++mi) {                                            \
      _Pragma("unroll")                                                         \
      for (int ni = 0; ni < 2; ++ni) {                                          \
        acc[(mh_) * 4 + mi][(nh_) * 2 + ni] =                                   \
            __builtin_amdgcn_mfma_f32_16x16x32_bf16(                            \
                a[mi][0], breg[ni][0], acc[(mh_) * 4 + mi][(nh_) * 2 + ni],     \
                0, 0, 0);                                                       \
        acc[(mh_) * 4 + mi][(nh_) * 2 + ni] =                                   \
            __builtin_amdgcn_mfma_f32_16x16x32_bf16(                            \
                a[mi][1], breg[ni][1], acc[(mh_) * 4 + mi][(nh_) * 2 + ni],     \
                0, 0, 0);                                                       \
      }                                                                         \
    }                                                                           \
    __builtin_amdgcn_s_setprio(0);                                              \
  } while (0)

#define BAR1() __builtin_amdgcn_s_barrier()
// reads-complete fence before barrier#2: cross-wave overwrite safety anchor
#define SYNC_END() do {                                                         \
    asm volatile("s_waitcnt lgkmcnt(0)" ::: "memory");                          \
    __builtin_amdgcn_s_barrier();                                               \
  } while (0)

  // prologue: tile0 all 4 halves FIRST (vmcnt(6) => first 8 loads landed),
  // then tile1 A.h0, A.h1, B.h0 (B.h1(1) is issued in tile0 ph1).
  ISSUE_H(0, 0); ISSUE_H(0, 1); ISSUE_H(0, 2); ISSUE_H(0, 3);
  ISSUE_H(1, 0); ISSUE_H(1, 2); ISSUE_H(1, 1);
  asm volatile("s_waitcnt vmcnt(6)" ::: "memory");  // tile 0 fully landed
  __builtin_amdgcn_s_barrier();

#pragma unroll 2
  for (int T = 0; T < NKT; ++T) {
    const int buf = T & 1;
    // phase 1: quadrant (0,0)
    READA(buf, 0);
    READB(buf, 0, b0);
    ISSUE_H(T + 1, 3);           // B.h1(T+1) -> Bs[buf^1] h1
    BAR1();
    MMA(0, 0, b0);
    SYNC_END();
    // phase 2: quadrant (0,1) — no issue
    READB(buf, 1, b1);
    BAR1();
    MMA(0, 1, b1);
    SYNC_END();
    // phase 3: quadrant (1,1)
    READA(buf, 1);
    ISSUE_H(T + 2, 1);           // B.h0(T+2) -> Bs[buf] h0 (B reads done ph2)
    BAR1();
    MMA(1, 1, b1);
    SYNC_END();
    // phase 4: quadrant (1,0)
    ISSUE_H(T + 2, 0);           // A.h0(T+2) -> As[buf] (A reads done ph3)
    ISSUE_H(T + 2, 2);           // A.h1(T+2)
    if (T < NKT - 2)
      asm volatile("s_waitcnt vmcnt(6)" ::: "memory");   // tile T+1 landed
    else
      asm volatile("s_waitcnt vmcnt(0)" ::: "memory");   // final drain
    BAR1();
    MMA(1, 0, b0);
    SYNC_END();
  }

  // epilogue: C/D lane map col=lane&15, row=(lane>>4)*4+e (m89-verified)
  const int q4 = lane >> 4;
#pragma unroll
  for (int ni = 0; ni < 4; ++ni) {
    const int col = n0 + wc * 64 + ni * 16 + r;
    const float sc = scale[col];
    const float bs = bias[col];
#pragma unroll
    for (int mi = 0; mi < 8; ++mi) {
      const int row = m0 + wr * 128 + mi * 16 + q4 * 4;
#pragma unroll
      for (int e = 0; e < 4; ++e)
        out[(size_t)(row + e) * DOUT + col] = acc[mi][ni][e] * sc + bs;
    }
  }
#undef ISSUE_H
#undef READA
#undef READB
#undef MMA
#undef BAR1
#undef SYNC_END
}

// ---------------------------------------------------------------------------
// Fallback (small workspace): 128^2 reg-staged kernel from round 1
// ---------------------------------------------------------------------------
__global__ __launch_bounds__(256, 2) void gemm128_kernel(
    const float* __restrict__ X, const ushort* __restrict__ QW,
    const float* __restrict__ scale, const float* __restrict__ bias,
    float* __restrict__ out) {
  __shared__ ushort Al[2][128 * BK32];
  __shared__ ushort Bl[2][128 * BK32];

  const int t = threadIdx.x;
  const int lane = t & 63;
  const int wid = t >> 6;
  const int wr = wid >> 1, wc = wid & 1;
  const int m0 = blockIdx.x * 128;
  const int n0 = blockIdx.y * 128;

  f32x4 acc[4][4] = {};
  const ushort* bg = QW + (size_t)n0 * DIN;
  const float*  ag = X  + (size_t)m0 * DIN;
  float4 areg[4];

  auto stageB = [&](int kt, int buf) {
    const ushort* src = bg + kt * BK32;
#pragma unroll
    for (int i = 0; i < 2; ++i)
      glds16(src + (size_t)(i * 64 + (t >> 2)) * DIN + (t & 3) * 8,
             &Bl[buf][(i * 256 + t) * 8]);
  };
  auto loadA_reg = [&](int kt) {
#pragma unroll
    for (int j = 0; j < 4; ++j)
      areg[j] = *reinterpret_cast<const float4*>(
          ag + (size_t)(j * 32 + (t >> 3)) * DIN + kt * BK32 + (t & 7) * 4);
  };
  auto writeA_reg = [&](int buf) {
#pragma unroll
    for (int j = 0; j < 4; ++j) {
      ushort4 o;
      o.x = f2bf(areg[j].x); o.y = f2bf(areg[j].y);
      o.z = f2bf(areg[j].z); o.w = f2bf(areg[j].w);
      *reinterpret_cast<ushort4*>(&Al[buf][(j * 256 + t) * 4]) = o;
    }
  };
  auto compute = [&](int buf) {
    const int r = lane & 15;
    const int kq = lane >> 4;
    bf16x8 af[4], bfr[4];
#pragma unroll
    for (int mi = 0; mi < 4; ++mi)
      af[mi] = *reinterpret_cast<const bf16x8*>(
          &Al[buf][(wr * 64 + mi * 16 + r) * BK32 + kq * 8]);
#pragma unroll
    for (int ni = 0; ni < 4; ++ni)
      bfr[ni] = *reinterpret_cast<const bf16x8*>(
          &Bl[buf][(wc * 64 + ni * 16 + r) * BK32 + kq * 8]);
#pragma unroll
    for (int mi = 0; mi < 4; ++mi)
#pragma unroll
      for (int ni = 0; ni < 4; ++ni)
        acc[mi][ni] = __builtin_amdgcn_mfma_f32_16x16x32_bf16(
            af[mi], bfr[ni], acc[mi][ni], 0, 0, 0);
  };

  loadA_reg(0);
  stageB(0, 0);
  writeA_reg(0);
  __syncthreads();

  int cur = 0;
  for (int kt = 0; kt < KT128; ++kt) {
    if (kt + 1 < KT128) {
      loadA_reg(kt + 1);
      stageB(kt + 1, cur ^ 1);
    }
    compute(cur);
    if (kt + 1 < KT128) {
      writeA_reg(cur ^ 1);
      __syncthreads();
      cur ^= 1;
    }
  }

  const int r = lane & 15;
  const int q4 = lane >> 4;
#pragma unroll
  for (int ni = 0; ni < 4; ++ni) {
    const int col = n0 + wc * 64 + ni * 16 + r;
    const float sc = scale[col];
    const float bs = bias[col];
#pragma unroll
    for (int mi = 0; mi < 4; ++mi) {
      const int row = m0 + wr * 64 + mi * 16 + q4 * 4;
#pragma unroll
      for (int e = 0; e < 4; ++e)
        out[(size_t)(row + e) * DOUT + col] = acc[mi][ni][e] * sc + bs;
    }
  }
}

extern "C" void kernel_launch(void* const* d_in, const int* in_sizes, int n_in,
                              void* d_out, int out_size, void* d_ws, size_t ws_size,
                              hipStream_t stream) {
  const float* X     = (const float*)d_in[0];
  const float* W     = (const float*)d_in[1];
  const float* scale = (const float*)d_in[2];
  const float* bias  = (const float*)d_in[3];
  float* out = (float*)d_out;

  const size_t qw_bytes = (size_t)DOUT * DIN * sizeof(ushort);  // 32 MB
  const size_t xb_bytes = (size_t)MTOT * DIN * sizeof(ushort);  // 64 MB
  ushort* QW = (ushort*)d_ws;
  ushort* XB = (ushort*)((char*)d_ws + qw_bytes);

  quant_kernel<<<DOUT, 256, 0, stream>>>(W, QW);

  if (ws_size >= qw_bytes + xb_bytes) {
    cvt_kernel<<<2048, 256, 0, stream>>>(X, XB, MTOT * DIN / 4);
    dim3 grid(MTOT / 256, DOUT / 256);
    gemm256_kernel<<<grid, 512, 0, stream>>>(XB, QW, scale, bias, out);
  } else {
    dim3 grid(MTOT / 128, DOUT / 128);
    gemm128_kernel<<<grid, 256, 0, stream>>>(X, QW, scale, bias, out);
  }
}